// Round 9
// baseline (136.377 us; speedup 1.0000x reference)
//
#include <hip/hip_runtime.h>
#include <hip/hip_bf16.h>
#include <cstdint>

// Problem constants: B=4, C=feat=64, N=H*W=4096.
#define BB 4
#define CC 64
#define NN 4096
#define NWRD 64          // 4096 bits / 64 per mask row
#define TAU 0.005f
#define EPSN 1e-5f

typedef __attribute__((ext_vector_type(8))) short short8;      // 8x16b (4 VGPRs)
typedef __attribute__((ext_vector_type(8))) _Float16 half8;    // 8 fp16 (4 VGPRs)
typedef __attribute__((ext_vector_type(4))) float f32x4;
typedef unsigned long long ull;

__device__ inline unsigned int bf16_rne(float v) {
    unsigned int u = __float_as_uint(v);
    return (u + 0x7FFFu + ((u >> 16) & 1u)) >> 16;
}

// mask layout: WORD-MAJOR  mask_t[b][jw (0..63)][n (0..4095)]  (ull elements).

// ---------------- K1: LDS-tiled transpose -> row-normalized FP16 y; zero deg ----
__global__ __launch_bounds__(256) void k_transpose(const float* __restrict__ x,
                                                   unsigned short* __restrict__ ynf,
                                                   int* __restrict__ deg) {
    __shared__ float lds[64 * 65];
    int t = threadIdx.x;
    int b = blockIdx.y;
    int n0 = blockIdx.x * 64;
    int gid = (b * (NN / 64) + blockIdx.x) * 256 + t;
    if (gid < BB * NN) deg[gid] = 0;          // zero for k_corr's atomics
    #pragma unroll
    for (int i = 0; i < 4; ++i) {
        int c = i * 16 + (t >> 4);
        int nc = (t & 15) * 4;
        float4 v = *(const float4*)(x + ((size_t)(b * CC + c)) * NN + n0 + nc);
        lds[c * 65 + nc + 0] = v.x;
        lds[c * 65 + nc + 1] = v.y;
        lds[c * 65 + nc + 2] = v.z;
        lds[c * 65 + nc + 3] = v.w;
    }
    __syncthreads();
    int l = t & 63, wv = t >> 6;
    for (int i = 0; i < 16; ++i) {
        int n = wv * 16 + i;
        float v = lds[l * 65 + n];
        float s = v * v;
        #pragma unroll
        for (int off = 32; off; off >>= 1) s += __shfl_xor(s, off, 64);
        float yv = v * rsqrtf(s);
        _Float16 hv = (_Float16)yv;            // RNE cast
        size_t row = (size_t)(b * NN + n0 + n);
        ynf[row * CC + l] = __builtin_bit_cast(unsigned short, hv);
    }
}

// ---------------- K2: MFMA correlation — TRIANGULAR (G symmetric), FP16 --------
// v3: NO LDS staging (R2/R8 lesson: ynf is L2-resident; staging's 4x reuse isn't
// worth 2 barriers/chunk + address VALU). Barrier-free main loop, direct global
// fp16 B loads; LDS = 10 KB mirror-transpose scratch only -> higher occupancy.
// Block = pair (I<=J); 4 waves x 64 n; 16 m-subtiles of 16.
__global__ __launch_bounds__(256) void k_corr(const unsigned short* __restrict__ ynf,
                                              ull* __restrict__ mask,
                                              int* __restrict__ deg) {
    __shared__ ull sh[256 * 5];                  // 10 KB mirror scratch
    int t = threadIdx.x;
    int l = t & 63, wv = t >> 6;
    int lc = l & 15, q = l >> 4;
    int b = blockIdx.z;
    // decode triangular pair index -> (I, J), I<=J, 136 pairs
    int idx = blockIdx.x, I = 0;
    while (idx >= 16 - I) { idx -= 16 - I; ++I; }
    int J = I + idx;
    int n0 = I * 256 + wv * 64;
    int m0 = J * 256;
    const unsigned short* bH = ynf + (size_t)b * NN * CC;

    half8 ah[4][2];
    #pragma unroll
    for (int nt = 0; nt < 4; ++nt)
        #pragma unroll
        for (int ks = 0; ks < 2; ++ks) {
            size_t off = (size_t)(n0 + nt * 16 + lc) * CC + (ks * 4 + q) * 8;
            ah[nt][ks] = *(const half8*)(bH + off);
        }

    int rr = l & 15;
    int rsel = rr & 3;
    int qq = rr >> 2;
    int myq = l >> 4;        // this lane's n-tile (0..3); lane l owns row n0+l

    ull wout[4] = {0ull, 0ull, 0ull, 0ull};
    #pragma unroll
    for (int tt = 0; tt < 16; ++tt) {            // m-subtile m0 + tt*16
        half8 bh[2];
        #pragma unroll
        for (int ks = 0; ks < 2; ++ks)
            bh[ks] = *(const half8*)(bH + (size_t)(m0 + tt * 16 + lc) * CC + (ks * 4 + q) * 8);
        #pragma unroll
        for (int nt = 0; nt < 4; ++nt) {
            f32x4 acc = {0.f, 0.f, 0.f, 0.f};
            #pragma unroll
            for (int ks = 0; ks < 2; ++ks)
                acc = __builtin_amdgcn_mfma_f32_16x16x32_f16(ah[nt][ks], bh[ks], acc, 0, 0, 0);
            ull bal[4];
            #pragma unroll
            for (int r = 0; r < 4; ++r)
                bal[r] = __ballot(acc[r] > TAU);
            ull sa = (rsel & 1) ? bal[1] : bal[0];
            ull sb = (rsel & 1) ? bal[3] : bal[2];
            ull sel = (rsel & 2) ? sb : sa;
            ull part = ((sel >> (qq * 16)) & 0xFFFFull) << ((tt & 3) * 16);
            if (myq == nt) wout[tt >> 2] |= part;
        }
    }
    int degacc = __popcll(wout[0]) + __popcll(wout[1])
               + __popcll(wout[2]) + __popcll(wout[3]);

    // direct tile: word-major layout -> lane-contiguous 512B stores per word
    int row = b * NN + n0 + l;
    #pragma unroll
    for (int c = 0; c < 4; ++c)
        mask[((size_t)(b * NWRD + J * 4 + c)) * NN + n0 + l] = wout[c];
    atomicAdd(&deg[row], degacc);

    if (J > I) {
        // mirror tile: rows in J-block, words I*4..I*4+3, via 64x64 bit transpose
        #pragma unroll
        for (int c = 0; c < 4; ++c) sh[(wv * 64 + l) * 5 + c] = wout[c];
        __syncthreads();
        const ull Mv[6] = {0x00000000FFFFFFFFull, 0x0000FFFF0000FFFFull,
                           0x00FF00FF00FF00FFull, 0x0F0F0F0F0F0F0F0Full,
                           0x3333333333333333ull, 0x5555555555555555ull};
        int dm = 0;
        ull tw[4];
        #pragma unroll
        for (int a = 0; a < 4; ++a) {
            // gather: lane l takes n-row (a*64+l)'s word for m-subblock wv
            ull xv = sh[(a * 64 + l) * 5 + wv];
            int dd = 32;
            #pragma unroll
            for (int s = 0; s < 6; ++s, dd >>= 1) {   // 64x64 bit transpose
                ull y = __shfl_xor(xv, dd, 64);
                ull M = Mv[s];
                xv = (l & dd) ? ((xv & ~M) | ((y >> dd) & M))
                              : ((xv & M) | ((y << dd) & ~M));
            }
            tw[a] = xv;
            dm += __popcll(xv);
        }
        int mrow = b * NN + J * 256 + wv * 64 + l;
        #pragma unroll
        for (int a = 0; a < 4; ++a)
            mask[((size_t)(b * NWRD + I * 4 + a)) * NN + J * 256 + wv * 64 + l] = tw[a];
        atomicAdd(&deg[mrow], dm);
    }
}

// ---------------- K3: pack y = dinv.*x^T into MFMA b-frag (k-packed) order, bf16
// Reads x DIRECTLY — no xt intermediate.
__global__ __launch_bounds__(256) void k_pack(const float* __restrict__ x,
                                              const int* __restrict__ deg,
                                              unsigned short* __restrict__ yph) {
    __shared__ float lp[32 * 65];
    int t = threadIdx.x;
    int kt = blockIdx.x;                 // 0..127 (32-n slab)
    int b = blockIdx.y;
    #pragma unroll
    for (int i = 0; i < 2; ++i) {
        int idx = i * 256 + t;                 // 0..511
        int c = idx >> 3;                      // channel 0..63
        int nq = (idx & 7) * 4;                // n within 32-slab
        float4 v = *(const float4*)(x + ((size_t)(b * CC + c)) * NN + kt * 32 + nq);
        lp[(nq + 0) * 65 + c] = v.x;
        lp[(nq + 1) * 65 + c] = v.y;
        lp[(nq + 2) * 65 + c] = v.z;
        lp[(nq + 3) * 65 + c] = v.w;
    }
    __syncthreads();
    size_t obase = (size_t)b * NN * CC + (size_t)kt * 2048;
    int kin = t & 31;
    int chi = t >> 5;
    float d = rsqrtf((float)deg[b * NN + kt * 32 + kin]);
    #pragma unroll
    for (int g8 = 0; g8 < 8; ++g8) {
        int c = g8 * 8 + chi;
        yph[obase + c * 32 + kin] = (unsigned short)bf16_rne(lp[kin * 65 + c] * d);
    }
}

// ---------------- K4: FUSED diffusion GEMM + reduce + W-GEMM + instnorm + relu ---
// 32 n-rows/block, 512 threads (8 waves), wave wv owns m in [wv*512, +512) as
// 8 chunks of 64 m; barrier-free main loop with direct global B loads (L2-hot).
// red LDS = 69.6 KB -> 2 blocks/CU, 16 waves/CU (50% occupancy).
// Grid (NN/32, BB) = 512 blocks.
__global__ __launch_bounds__(512, 4) void k_fused(const ull* __restrict__ mask,
                                                  const unsigned short* __restrict__ yph,
                                                  const int* __restrict__ deg,
                                                  const float* __restrict__ W,
                                                  float* __restrict__ xout,
                                                  unsigned short* __restrict__ xpack) {
    __shared__ __align__(16) float red[8 * 32][68];   // 69,632 B; stride 68 pads banks

    int t = threadIdx.x;
    int l = t & 63, wv = t >> 6;                  // 8 waves
    int lc = l & 15, q = l >> 4;
    int b = blockIdx.y;
    int n0 = blockIdx.x * 32;
    const unsigned short* src = yph + (size_t)b * NN * CC;

    f32x4 acc[2][4];
    #pragma unroll
    for (int nt = 0; nt < 2; ++nt)
        #pragma unroll
        for (int tt = 0; tt < 4; ++tt) acc[nt][tt] = f32x4{0.f, 0.f, 0.f, 0.f};

    // barrier-free main loop: chunk ch covers m = wv*512 + ch*64 (word wv*8+ch)
    #pragma unroll
    for (int ch = 0; ch < 8; ++ch) {
        ull mwc[2];
        #pragma unroll
        for (int nt = 0; nt < 2; ++nt)
            mwc[nt] = mask[((size_t)(b * NWRD + wv * 8 + ch)) * NN + n0 + nt * 16 + lc];
        int g0 = wv * 16 + ch * 2;                // 32-m group index
        #pragma unroll
        for (int kt = 0; kt < 2; ++kt) {
            const unsigned short* bsrc = src + (size_t)(g0 + kt) * 2048;
            short8 bf[4];
            #pragma unroll
            for (int tt = 0; tt < 4; ++tt)
                bf[tt] = *(const short8*)&bsrc[(tt * 16 + lc) * 32 + q * 8];
            union { unsigned int u[4]; short8 v; } a[2];
            #pragma unroll
            for (int nt = 0; nt < 2; ++nt) {
                unsigned int bits = (unsigned int)(mwc[nt] >> (kt * 32 + q * 8)) & 0xFFu;
                #pragma unroll
                for (int j = 0; j < 4; ++j)
                    a[nt].u[j] = ((bits >> (2 * j)) & 1u ? 0x3F80u : 0u)
                               | ((bits >> (2 * j + 1)) & 1u ? 0x3F800000u : 0u);
            }
            #pragma unroll
            for (int tt = 0; tt < 4; ++tt)
                #pragma unroll
                for (int nt = 0; nt < 2; ++nt)
                    acc[nt][tt] = __builtin_amdgcn_mfma_f32_16x16x32_bf16(a[nt].v, bf[tt], acc[nt][tt], 0, 0, 0);
        }
    }

    // ---- cross-wave reduction: each wave dumps its 32x64 f32 tile ----
    #pragma unroll
    for (int nt = 0; nt < 2; ++nt)
        #pragma unroll
        for (int tt = 0; tt < 4; ++tt)
            #pragma unroll
            for (int r = 0; r < 4; ++r)
                red[wv * 32 + nt * 16 + q * 4 + r][tt * 16 + lc] = acc[nt][tt][r];
    __syncthreads();

    // thread t sums 8 tiles for row n = t>>4, cols c0..c0+3; scale by deg^-1/2
    {
        int n = t >> 4, c0 = (t & 15) * 4;
        float dRow = rsqrtf((float)deg[b * NN + n0 + n]);
        float s[4] = {0.f, 0.f, 0.f, 0.f};
        #pragma unroll
        for (int w = 0; w < 8; ++w) {
            const float* rp = &red[w * 32 + n][c0];
            #pragma unroll
            for (int j = 0; j < 4; ++j) s[j] += rp[j];
        }
        float* wp = &red[n][c0];
        #pragma unroll
        for (int j = 0; j < 4; ++j) wp[j] = s[j] * dRow;
    }
    __syncthreads();

    // ---- epilogue: wave wv handles rows wv*4..wv*4+3; lane = output feature ----
    float Wreg[64];                                // W[:, lane]; coalesced across lanes
    #pragma unroll
    for (int c = 0; c < 64; ++c) Wreg[c] = W[c * 64 + l];
    ull xv = 0;                                    // 4 packed bf16 next-layer values
    #pragma unroll
    for (int tI = 0; tI < 4; ++tI) {
        int nn = wv * 4 + tI;
        int grow = b * NN + n0 + nn;
        float h = 0.f;
        #pragma unroll
        for (int c4 = 0; c4 < 16; ++c4) {
            float4 s4 = *(const float4*)&red[nn][c4 * 4];   // broadcast b128
            h += s4.x * Wreg[c4 * 4 + 0] + s4.y * Wreg[c4 * 4 + 1]
               + s4.z * Wreg[c4 * 4 + 2] + s4.w * Wreg[c4 * 4 + 3];
        }
        float mean = h;
        #pragma unroll
        for (int off = 32; off; off >>= 1) mean += __shfl_xor(mean, off, 64);
        mean *= (1.f / 64.f);
        float dv = h - mean;
        float var = dv * dv;
        #pragma unroll
        for (int off = 32; off; off >>= 1) var += __shfl_xor(var, off, 64);
        var *= (1.f / 64.f);
        float o = dv * rsqrtf(var + EPSN);
        o = o > 0.f ? o : 0.f;
        if (xout)
            xout[(size_t)grow * CC + l] = o;
        if (xpack) {                               // defer: pack bf16(o * dinv_n) in regs
            float dR = rsqrtf((float)deg[grow]);
            xv |= (ull)(unsigned short)bf16_rne(o * dR) << (16 * tI);
        }
    }
    if (xpack) {
        // rows n0+wv*4..+3 at feature l are contiguous in k-packed layout: one 8B store
        size_t base = (size_t)b * NN * CC + (size_t)(n0 >> 5) * 2048
                    + (size_t)l * 32 + (size_t)wv * 4;
        *(ull*)&xpack[base] = xv;
    }
}

extern "C" void kernel_launch(void* const* d_in, const int* in_sizes, int n_in,
                              void* d_out, int out_size, void* d_ws, size_t ws_size,
                              hipStream_t stream) {
    const float* x  = (const float*)d_in[0];
    const float* W0 = (const float*)d_in[1];
    const float* W1 = (const float*)d_in[2];
    float* out = (float*)d_out;

    char* ws = (char*)d_ws;
    // Workspace layout (~14.1 MiB used)
    ull* mask = (ull*)(ws);                                           // 8 MiB (word-major)
    unsigned short* ynf = (unsigned short*)(ws + ((size_t)8 << 20));  // 2 MiB (fp16 y)
    unsigned short* xp0 = (unsigned short*)(ws + ((size_t)10 << 20)); // 2 MiB
    unsigned short* xp1 = (unsigned short*)(ws + ((size_t)12 << 20)); // 2 MiB
    int* deg = (int*)(ws + ((size_t)14 << 20));                       // 64 KiB

    // Build adjacency (deg zeroed in k_transpose, accumulated in k_corr)
    k_transpose<<<dim3(NN / 64, BB), 256, 0, stream>>>(x, ynf, deg);
    k_corr<<<dim3(136, 1, BB), 256, 0, stream>>>(ynf, mask, deg);

    // Layer 1 (fused diffusion + out): writes packed input for layer 2
    k_pack<<<dim3(128, BB), 256, 0, stream>>>(x, deg, xp0);
    k_fused<<<dim3(NN / 32, BB), 512, 0, stream>>>(mask, xp0, deg, W0, nullptr, xp1);

    // Layer 2 (fused): writes final output
    k_fused<<<dim3(NN / 32, BB), 512, 0, stream>>>(mask, xp1, deg, W1, out, nullptr);
}

// Round 10
// 133.865 us; speedup vs baseline: 1.0188x; 1.0188x over previous
//
#include <hip/hip_runtime.h>
#include <hip/hip_bf16.h>
#include <cstdint>

// Problem constants: B=4, C=feat=64, N=H*W=4096.
#define BB 4
#define CC 64
#define NN 4096
#define NWRD 64          // 4096 bits / 64 per mask row
#define TAU 0.005f
#define EPSN 1e-5f

typedef __attribute__((ext_vector_type(8))) short short8;      // 8x16b (4 VGPRs)
typedef __attribute__((ext_vector_type(8))) _Float16 half8;    // 8 fp16 (4 VGPRs)
typedef __attribute__((ext_vector_type(4))) float f32x4;
typedef unsigned long long ull;

__device__ inline unsigned int bf16_rne(float v) {
    unsigned int u = __float_as_uint(v);
    return (u + 0x7FFFu + ((u >> 16) & 1u)) >> 16;
}

// async 16B global->LDS copy: LDS dest = wave-uniform base + lane*16 [m97/m104]
__device__ inline void gload_lds16(const void* g, void* lds_base) {
    __builtin_amdgcn_global_load_lds(
        (const __attribute__((address_space(1))) unsigned int*)g,
        (__attribute__((address_space(3))) unsigned int*)lds_base, 16, 0, 0);
}

// mask layout: WORD-MAJOR  mask_t[b][jw (0..63)][n (0..4095)]  (ull elements).

// ---------------- K1: LDS-tiled transpose -> row-normalized FP16 y; zero deg ----
// fp16 single-precision path (was bf16 hi/lo x2): y unit-normalized, fp32 MFMA
// accumulate => corr abs error ~7e-5 << TAU threshold granularity.
__global__ __launch_bounds__(256) void k_transpose(const float* __restrict__ x,
                                                   unsigned short* __restrict__ ynf,
                                                   int* __restrict__ deg) {
    __shared__ float lds[64 * 65];
    int t = threadIdx.x;
    int b = blockIdx.y;
    int n0 = blockIdx.x * 64;
    int gid = (b * (NN / 64) + blockIdx.x) * 256 + t;
    if (gid < BB * NN) deg[gid] = 0;          // zero for k_corr's atomics
    #pragma unroll
    for (int i = 0; i < 4; ++i) {
        int c = i * 16 + (t >> 4);
        int nc = (t & 15) * 4;
        float4 v = *(const float4*)(x + ((size_t)(b * CC + c)) * NN + n0 + nc);
        lds[c * 65 + nc + 0] = v.x;
        lds[c * 65 + nc + 1] = v.y;
        lds[c * 65 + nc + 2] = v.z;
        lds[c * 65 + nc + 3] = v.w;
    }
    __syncthreads();
    int l = t & 63, wv = t >> 6;
    for (int i = 0; i < 16; ++i) {
        int n = wv * 16 + i;
        float v = lds[l * 65 + n];
        float s = v * v;
        #pragma unroll
        for (int off = 32; off; off >>= 1) s += __shfl_xor(s, off, 64);
        float yv = v * rsqrtf(s);
        _Float16 hv = (_Float16)yv;            // RNE cast
        size_t row = (size_t)(b * NN + n0 + n);
        ynf[row * CC + l] = __builtin_bit_cast(unsigned short, hv);
    }
}

// ---------------- K2: MFMA correlation — TRIANGULAR (G symmetric), FP16 --------
// Block = pair (I<=J) of 256-row blocks; 4 waves x 64 n; sweeps J's 256 m in 2
// async-dbuf chunks of 128. ONE f16 MFMA per (tt,nt,ks). LDS staging KEPT:
// R9 A/B showed direct global loads regress +2.3us (staging = 4x cross-wave
// panel reuse + coalesced gload_lds16; unlike k_fused where slices are private).
#define CORR_MC 128
__global__ __launch_bounds__(256) void k_corr(const unsigned short* __restrict__ ynf,
                                              ull* __restrict__ mask,
                                              int* __restrict__ deg) {
    __shared__ unsigned short ldsH[2][CORR_MC * 64];   // 2 x 16 KB
    int t = threadIdx.x;
    int l = t & 63, wv = t >> 6;
    int lc = l & 15, q = l >> 4;
    int b = blockIdx.z;
    // decode triangular pair index -> (I, J), I<=J, 136 pairs
    int idx = blockIdx.x, I = 0;
    while (idx >= 16 - I) { idx -= 16 - I; ++I; }
    int J = I + idx;
    int n0 = I * 256 + wv * 64;
    int m0 = J * 256;
    const unsigned short* bH = ynf + (size_t)b * NN * CC;

    half8 ah[4][2];
    #pragma unroll
    for (int nt = 0; nt < 4; ++nt)
        #pragma unroll
        for (int ks = 0; ks < 2; ++ks) {
            size_t off = (size_t)(n0 + nt * 16 + lc) * CC + (ks * 4 + q) * 8;
            ah[nt][ks] = *(const half8*)(bH + off);
        }

    int rr = l & 15;
    int rsel = rr & 3;
    int qq = rr >> 2;
    int myq = l >> 4;        // this lane's n-tile (0..3); lane l owns row n0+l

    auto stage = [&](int mc, int bufi) {
        int mbase = m0 + mc * CORR_MC;
        #pragma unroll
        for (int rd = 0; rd < 4; ++rd) {
            int gu = rd * 256 + wv * 64;               // wave-uniform part
            int g = gu + l;
            int ci = (g & ~7) | ((g & 7) ^ ((g >> 3) & 7));   // pre-permute for swizzle
            gload_lds16(bH + (size_t)mbase * CC + ci * 8, &ldsH[bufi][gu * 8]);
        }
    };

    ull wout[4];
    int degacc = 0;
    stage(0, 0);
    for (int mc = 0; mc < 2; ++mc) {
        __syncthreads();
        if (mc == 0) stage(1, 1);
        int bufi = mc & 1;
        ull w0 = 0, w1 = 0;
        #pragma unroll
        for (int tt = 0; tt < 8; ++tt) {
            half8 bh[2];
            #pragma unroll
            for (int ks = 0; ks < 2; ++ks) {
                int rowm = tt * 16 + lc;
                int sw = ((ks * 4 + q) ^ (rowm & 7)) * 8;
                bh[ks] = *(const half8*)&ldsH[bufi][rowm * 64 + sw];
            }
            #pragma unroll
            for (int nt = 0; nt < 4; ++nt) {
                f32x4 acc = {0.f, 0.f, 0.f, 0.f};
                #pragma unroll
                for (int ks = 0; ks < 2; ++ks)
                    acc = __builtin_amdgcn_mfma_f32_16x16x32_f16(ah[nt][ks], bh[ks], acc, 0, 0, 0);
                ull bal[4];
                #pragma unroll
                for (int r = 0; r < 4; ++r)
                    bal[r] = __ballot(acc[r] > TAU);
                ull sa = (rsel & 1) ? bal[1] : bal[0];
                ull sb = (rsel & 1) ? bal[3] : bal[2];
                ull sel = (rsel & 2) ? sb : sa;
                ull part = ((sel >> (qq * 16)) & 0xFFFFull) << ((tt & 3) * 16);
                if (myq == nt) { if (tt < 4) w0 |= part; else w1 |= part; }
            }
        }
        wout[mc * 2 + 0] = w0;
        wout[mc * 2 + 1] = w1;
        degacc += __popcll(w0) + __popcll(w1);
    }

    // direct tile: word-major layout -> lane-contiguous 512B stores per word
    int row = b * NN + n0 + l;
    #pragma unroll
    for (int c = 0; c < 4; ++c)
        mask[((size_t)(b * NWRD + J * 4 + c)) * NN + n0 + l] = wout[c];
    atomicAdd(&deg[row], degacc);

    if (J > I) {
        // mirror tile: rows in J-block, words I*4..I*4+3, via bit transpose
        __syncthreads();
        ull* sh = (ull*)&ldsH[0][0];         // reuse staging LDS (10 KB needed)
        #pragma unroll
        for (int c = 0; c < 4; ++c) sh[(wv * 64 + l) * 5 + c] = wout[c];
        __syncthreads();
        const ull Mv[6] = {0x00000000FFFFFFFFull, 0x0000FFFF0000FFFFull,
                           0x00FF00FF00FF00FFull, 0x0F0F0F0F0F0F0F0Full,
                           0x3333333333333333ull, 0x5555555555555555ull};
        int dm = 0;
        ull tw[4];
        #pragma unroll
        for (int a = 0; a < 4; ++a) {
            // gather: lane l takes n-row (a*64+l)'s word for m-subblock wv
            ull xv = sh[(a * 64 + l) * 5 + wv];
            int dd = 32;
            #pragma unroll
            for (int s = 0; s < 6; ++s, dd >>= 1) {   // 64x64 bit transpose
                ull y = __shfl_xor(xv, dd, 64);
                ull M = Mv[s];
                xv = (l & dd) ? ((xv & ~M) | ((y >> dd) & M))
                              : ((xv & M) | ((y << dd) & ~M));
            }
            tw[a] = xv;
            dm += __popcll(xv);
        }
        int mrow = b * NN + J * 256 + wv * 64 + l;
        #pragma unroll
        for (int a = 0; a < 4; ++a)
            mask[((size_t)(b * NWRD + I * 4 + a)) * NN + J * 256 + wv * 64 + l] = tw[a];
        atomicAdd(&deg[mrow], dm);
    }
}

// ---------------- K3: pack y = dinv.*x^T into MFMA b-frag (k-packed) order, bf16
// Reads x DIRECTLY — no xt intermediate.
__global__ __launch_bounds__(256) void k_pack(const float* __restrict__ x,
                                              const int* __restrict__ deg,
                                              unsigned short* __restrict__ yph) {
    __shared__ float lp[32 * 65];
    int t = threadIdx.x;
    int kt = blockIdx.x;                 // 0..127 (32-n slab)
    int b = blockIdx.y;
    #pragma unroll
    for (int i = 0; i < 2; ++i) {
        int idx = i * 256 + t;                 // 0..511
        int c = idx >> 3;                      // channel 0..63
        int nq = (idx & 7) * 4;                // n within 32-slab
        float4 v = *(const float4*)(x + ((size_t)(b * CC + c)) * NN + kt * 32 + nq);
        lp[(nq + 0) * 65 + c] = v.x;
        lp[(nq + 1) * 65 + c] = v.y;
        lp[(nq + 2) * 65 + c] = v.z;
        lp[(nq + 3) * 65 + c] = v.w;
    }
    __syncthreads();
    size_t obase = (size_t)b * NN * CC + (size_t)kt * 2048;
    int kin = t & 31;
    int chi = t >> 5;
    float d = rsqrtf((float)deg[b * NN + kt * 32 + kin]);
    #pragma unroll
    for (int g8 = 0; g8 < 8; ++g8) {
        int c = g8 * 8 + chi;
        yph[obase + c * 32 + kin] = (unsigned short)bf16_rne(lp[kin * 65 + c] * d);
    }
}

// ---------------- K4: FUSED diffusion GEMM + reduce + W-GEMM + instnorm + relu ---
// 32 n-rows/block, 512 threads (8 waves), wave wv owns m in [wv*512, +512) as
// 8 chunks of 64 m; barrier-free main loop with direct global B loads (L2-hot;
// each wave's slice is PRIVATE -> staging would have zero reuse, R2-verified).
// red LDS = 69.6 KB -> 2 blocks/CU, 16 waves/CU (50% occupancy).
// Grid (NN/32, BB) = 512 blocks.
__global__ __launch_bounds__(512, 4) void k_fused(const ull* __restrict__ mask,
                                                  const unsigned short* __restrict__ yph,
                                                  const int* __restrict__ deg,
                                                  const float* __restrict__ W,
                                                  float* __restrict__ xout,
                                                  unsigned short* __restrict__ xpack) {
    __shared__ __align__(16) float red[8 * 32][68];   // 69,632 B; stride 68 pads banks

    int t = threadIdx.x;
    int l = t & 63, wv = t >> 6;                  // 8 waves
    int lc = l & 15, q = l >> 4;
    int b = blockIdx.y;
    int n0 = blockIdx.x * 32;
    const unsigned short* src = yph + (size_t)b * NN * CC;

    f32x4 acc[2][4];
    #pragma unroll
    for (int nt = 0; nt < 2; ++nt)
        #pragma unroll
        for (int tt = 0; tt < 4; ++tt) acc[nt][tt] = f32x4{0.f, 0.f, 0.f, 0.f};

    // barrier-free main loop: chunk ch covers m = wv*512 + ch*64 (word wv*8+ch)
    #pragma unroll
    for (int ch = 0; ch < 8; ++ch) {
        ull mwc[2];
        #pragma unroll
        for (int nt = 0; nt < 2; ++nt)
            mwc[nt] = mask[((size_t)(b * NWRD + wv * 8 + ch)) * NN + n0 + nt * 16 + lc];
        int g0 = wv * 16 + ch * 2;                // 32-m group index
        #pragma unroll
        for (int kt = 0; kt < 2; ++kt) {
            const unsigned short* bsrc = src + (size_t)(g0 + kt) * 2048;
            short8 bf[4];
            #pragma unroll
            for (int tt = 0; tt < 4; ++tt)
                bf[tt] = *(const short8*)&bsrc[(tt * 16 + lc) * 32 + q * 8];
            union { unsigned int u[4]; short8 v; } a[2];
            #pragma unroll
            for (int nt = 0; nt < 2; ++nt) {
                unsigned int bits = (unsigned int)(mwc[nt] >> (kt * 32 + q * 8)) & 0xFFu;
                #pragma unroll
                for (int j = 0; j < 4; ++j)
                    a[nt].u[j] = ((bits >> (2 * j)) & 1u ? 0x3F80u : 0u)
                               | ((bits >> (2 * j + 1)) & 1u ? 0x3F800000u : 0u);
            }
            #pragma unroll
            for (int tt = 0; tt < 4; ++tt)
                #pragma unroll
                for (int nt = 0; nt < 2; ++nt)
                    acc[nt][tt] = __builtin_amdgcn_mfma_f32_16x16x32_bf16(a[nt].v, bf[tt], acc[nt][tt], 0, 0, 0);
        }
    }

    // ---- cross-wave reduction: each wave dumps its 32x64 f32 tile ----
    #pragma unroll
    for (int nt = 0; nt < 2; ++nt)
        #pragma unroll
        for (int tt = 0; tt < 4; ++tt)
            #pragma unroll
            for (int r = 0; r < 4; ++r)
                red[wv * 32 + nt * 16 + q * 4 + r][tt * 16 + lc] = acc[nt][tt][r];
    __syncthreads();

    // thread t sums 8 tiles for row n = t>>4, cols c0..c0+3; scale by deg^-1/2
    {
        int n = t >> 4, c0 = (t & 15) * 4;
        float dRow = rsqrtf((float)deg[b * NN + n0 + n]);
        float s[4] = {0.f, 0.f, 0.f, 0.f};
        #pragma unroll
        for (int w = 0; w < 8; ++w) {
            const float* rp = &red[w * 32 + n][c0];
            #pragma unroll
            for (int j = 0; j < 4; ++j) s[j] += rp[j];
        }
        float* wp = &red[n][c0];
        #pragma unroll
        for (int j = 0; j < 4; ++j) wp[j] = s[j] * dRow;
    }
    __syncthreads();

    // ---- epilogue: wave wv handles rows wv*4..wv*4+3; lane = output feature ----
    float Wreg[64];                                // W[:, lane]; coalesced across lanes
    #pragma unroll
    for (int c = 0; c < 64; ++c) Wreg[c] = W[c * 64 + l];
    ull xv = 0;                                    // 4 packed bf16 next-layer values
    #pragma unroll
    for (int tI = 0; tI < 4; ++tI) {
        int nn = wv * 4 + tI;
        int grow = b * NN + n0 + nn;
        float h = 0.f;
        #pragma unroll
        for (int c4 = 0; c4 < 16; ++c4) {
            float4 s4 = *(const float4*)&red[nn][c4 * 4];   // broadcast b128
            h += s4.x * Wreg[c4 * 4 + 0] + s4.y * Wreg[c4 * 4 + 1]
               + s4.z * Wreg[c4 * 4 + 2] + s4.w * Wreg[c4 * 4 + 3];
        }
        float mean = h;
        #pragma unroll
        for (int off = 32; off; off >>= 1) mean += __shfl_xor(mean, off, 64);
        mean *= (1.f / 64.f);
        float dv = h - mean;
        float var = dv * dv;
        #pragma unroll
        for (int off = 32; off; off >>= 1) var += __shfl_xor(var, off, 64);
        var *= (1.f / 64.f);
        float o = dv * rsqrtf(var + EPSN);
        o = o > 0.f ? o : 0.f;
        if (xout)
            xout[(size_t)grow * CC + l] = o;
        if (xpack) {                               // defer: pack bf16(o * dinv_n) in regs
            float dR = rsqrtf((float)deg[grow]);
            xv |= (ull)(unsigned short)bf16_rne(o * dR) << (16 * tI);
        }
    }
    if (xpack) {
        // rows n0+wv*4..+3 at feature l are contiguous in k-packed layout: one 8B store
        size_t base = (size_t)b * NN * CC + (size_t)(n0 >> 5) * 2048
                    + (size_t)l * 32 + (size_t)wv * 4;
        *(ull*)&xpack[base] = xv;
    }
}

extern "C" void kernel_launch(void* const* d_in, const int* in_sizes, int n_in,
                              void* d_out, int out_size, void* d_ws, size_t ws_size,
                              hipStream_t stream) {
    const float* x  = (const float*)d_in[0];
    const float* W0 = (const float*)d_in[1];
    const float* W1 = (const float*)d_in[2];
    float* out = (float*)d_out;

    char* ws = (char*)d_ws;
    // Workspace layout (~14.1 MiB used)
    ull* mask = (ull*)(ws);                                           // 8 MiB (word-major)
    unsigned short* ynf = (unsigned short*)(ws + ((size_t)8 << 20));  // 2 MiB (fp16 y)
    unsigned short* xp0 = (unsigned short*)(ws + ((size_t)10 << 20)); // 2 MiB
    unsigned short* xp1 = (unsigned short*)(ws + ((size_t)12 << 20)); // 2 MiB
    int* deg = (int*)(ws + ((size_t)14 << 20));                       // 64 KiB

    // Build adjacency (deg zeroed in k_transpose, accumulated in k_corr)
    k_transpose<<<dim3(NN / 64, BB), 256, 0, stream>>>(x, ynf, deg);
    k_corr<<<dim3(136, 1, BB), 256, 0, stream>>>(ynf, mask, deg);

    // Layer 1 (fused diffusion + out): writes packed input for layer 2
    k_pack<<<dim3(128, BB), 256, 0, stream>>>(x, deg, xp0);
    k_fused<<<dim3(NN / 32, BB), 512, 0, stream>>>(mask, xp0, deg, W0, nullptr, xp1);

    // Layer 2 (fused): writes final output
    k_fused<<<dim3(NN / 32, BB), 512, 0, stream>>>(mask, xp1, deg, W1, out, nullptr);
}